// Round 1
// baseline (227.113 us; speedup 1.0000x reference)
//
#include <hip/hip_runtime.h>
#include <hip/hip_bf16.h>

// Problem constants (from reference setup_inputs)
#define BB 16        // batch
#define TT 288       // time steps
#define NN 4096      // nodes
#define FF 2         // features (only feature 0 used)
#define RR 16        // regions
#define HH 10        // horizon
#define TC 4         // time chunks for phase-1 parallelism
#define TSTEP (TT / TC)   // 72
#define NULLV (-1.0f)

// ---------------------------------------------------------------------------
// Kernel 1: per-(b, n, t-chunk) partial sum + valid count over TSTEP steps.
// Also block-reduces (sum, count) and atomically accumulates the GLOBAL
// valid sum / valid count needed for the imputation mean.
// grid = (NN/256, TC, BB), block = 256.  Reads the full 151 MB input.
// ---------------------------------------------------------------------------
__global__ __launch_bounds__(256) void k_partial(
    const float* __restrict__ x,
    float* __restrict__ psum, int* __restrict__ pcnt,
    float* __restrict__ gsum, unsigned int* __restrict__ gcnt) {
  const int tid = threadIdx.x;
  const int n   = blockIdx.x * 256 + tid;
  const int tc  = blockIdx.y;
  const int b   = blockIdx.z;

  const float* p = x + ((size_t)(b * TT + tc * TSTEP) * NN + n) * FF;
  float s = 0.0f;
  unsigned int c = 0;
#pragma unroll 8
  for (int t = 0; t < TSTEP; ++t) {
    float v = p[(size_t)t * (NN * FF)];
    bool valid = (v != NULLV);
    s += valid ? v : 0.0f;
    c += valid ? 1u : 0u;
  }
  const size_t o = ((size_t)tc * BB + b) * NN + n;
  psum[o] = s;
  pcnt[o] = (int)c;

  // wave (64-lane) shuffle reduce, then cross-wave LDS reduce, 1 atomic/block
  float rs = s;
  unsigned int rc = c;
  for (int off = 32; off > 0; off >>= 1) {
    rs += __shfl_down(rs, off);
    rc += __shfl_down(rc, off);
  }
  __shared__ float sh_s[4];
  __shared__ unsigned int sh_c[4];
  const int wid = tid >> 6;
  if ((tid & 63) == 0) { sh_s[wid] = rs; sh_c[wid] = rc; }
  __syncthreads();
  if (tid == 0) {
    float ts = sh_s[0] + sh_s[1] + sh_s[2] + sh_s[3];
    unsigned int tcnt = sh_c[0] + sh_c[1] + sh_c[2] + sh_c[3];
    atomicAdd(gsum, ts);
    atomicAdd(gcnt, tcnt);
  }
}

// ---------------------------------------------------------------------------
// Kernel 2: combine TC partials per (b,n), impute nulls with gmean, write the
// horizon-tiled prediction [B,H,N], and accumulate per-(b,region) sums via
// LDS histogram + 16 global atomics per block.
// grid = BB*NN/256, block = 256 (each block spans 256 consecutive n, one b).
// ---------------------------------------------------------------------------
__global__ __launch_bounds__(256) void k_pred(
    const float* __restrict__ psum, const int* __restrict__ pcnt,
    const float* __restrict__ gsum, const unsigned int* __restrict__ gcnt,
    const int* __restrict__ cluster,
    float* __restrict__ out, float* __restrict__ regsum) {
  const int tid = threadIdx.x;
  const int idx = blockIdx.x * 256 + tid;  // b*NN + n
  const int b = idx >> 12;                 // NN = 4096
  const int n = idx & (NN - 1);

  float s = 0.0f;
  int c = 0;
#pragma unroll
  for (int tc = 0; tc < TC; ++tc) {
    const size_t o = (size_t)tc * BB * NN + idx;
    s += psum[o];
    c += pcnt[o];
  }
  const float gmean = *gsum / fmaxf((float)(*gcnt), 1.0f);
  const float pred = (s + (float)(TT - c) * gmean) * (1.0f / (float)TT);

#pragma unroll
  for (int h = 0; h < HH; ++h)
    out[(size_t)(b * HH + h) * NN + n] = pred;

  __shared__ float rs[RR];
  if (tid < RR) rs[tid] = 0.0f;
  __syncthreads();
  atomicAdd(&rs[cluster[n]], pred);
  __syncthreads();
  if (tid < RR) atomicAdd(&regsum[b * RR + tid], rs[tid]);
}

// ---------------------------------------------------------------------------
// Kernel 3: single block. Build region histogram from cluster_id, divide the
// per-(b,region) sums, write horizon-tiled regional output [B,H,R].
// ---------------------------------------------------------------------------
__global__ __launch_bounds__(256) void k_final(
    const int* __restrict__ cluster, const float* __restrict__ regsum,
    float* __restrict__ out2) {
  __shared__ unsigned int hist[RR];
  const int tid = threadIdx.x;
  if (tid < RR) hist[tid] = 0u;
  __syncthreads();
  for (int i = tid; i < NN; i += 256) atomicAdd(&hist[cluster[i]], 1u);
  __syncthreads();
  const int b = tid >> 4;
  const int r = tid & 15;
  const float v = regsum[tid] / fmaxf((float)hist[r], 1.0f);
#pragma unroll
  for (int h = 0; h < HH; ++h)
    out2[(size_t)(b * HH + h) * RR + r] = v;
}

extern "C" void kernel_launch(void* const* d_in, const int* in_sizes, int n_in,
                              void* d_out, int out_size, void* d_ws, size_t ws_size,
                              hipStream_t stream) {
  const float* x       = (const float*)d_in[0];  // [B,T,N,F] fp32
  const int*   cluster = (const int*)d_in[1];    // [N] int32
  float* out = (float*)d_out;                    // [B,H,N] then [B,H,R]

  // Workspace layout:
  //   [0]        gsum   (float)
  //   [1]        gcnt   (uint)
  //   [2..258)   regsum (float, B*R = 256)
  //   @4096B     psum   (float, TC*B*N)
  //   @4096+1MB  pcnt   (int,   TC*B*N)
  float*        gsum   = (float*)d_ws;
  unsigned int* gcnt   = (unsigned int*)d_ws + 1;
  float*        regsum = (float*)d_ws + 2;
  float* psum = (float*)((char*)d_ws + 4096);
  int*   pcnt = (int*)((char*)d_ws + 4096 + (size_t)TC * BB * NN * sizeof(float));

  // zero the atomically-accumulated region (gsum, gcnt, regsum) — 4 KB
  hipMemsetAsync(d_ws, 0, 4096, stream);

  dim3 g1(NN / 256, TC, BB);
  k_partial<<<g1, 256, 0, stream>>>(x, psum, pcnt, gsum, gcnt);

  k_pred<<<(BB * NN) / 256, 256, 0, stream>>>(psum, pcnt, gsum, gcnt, cluster,
                                              out, regsum);

  k_final<<<1, 256, 0, stream>>>(cluster, regsum, out + (size_t)BB * HH * NN);
}

// Round 2
// 216.392 us; speedup vs baseline: 1.0495x; 1.0495x over previous
//
#include <hip/hip_runtime.h>
#include <hip/hip_bf16.h>

// Problem constants (from reference setup_inputs)
#define BB 16        // batch
#define TT 288       // time steps
#define NN 4096      // nodes
#define FF 2         // features (only feature 0 used)
#define RR 16        // regions
#define HH 10        // horizon
#define TC 8         // time chunks for phase-1 parallelism
#define TSTEP (TT / TC)   // 36
#define NBLK1 (8 * TC * BB)   // k_partial block count = 1024
#define NULLV (-1.0f)

// ---------------------------------------------------------------------------
// Kernel 1: grid (NN/512, TC, BB) = (8,8,16) = 1024 blocks, 256 threads.
// Each thread owns 2 consecutive nodes via float4 loads (nodes interleave
// with the 2 features, so one float4 = {n0.f0, n0.f1, n1.f0, n1.f1}).
// Writes per-(tc,b,n) partial sum/count (plain stores, no zeroing needed)
// and a per-block total (bsum/bcnt) for the global imputation mean.
// ---------------------------------------------------------------------------
__global__ __launch_bounds__(256) void k_partial(
    const float4* __restrict__ x4,
    float2* __restrict__ psum2, int2* __restrict__ pcnt2,
    float* __restrict__ bsum, unsigned int* __restrict__ bcnt) {
  const int tid = threadIdx.x;
  const int n0  = blockIdx.x * 512 + tid * 2;
  const int tc  = blockIdx.y;
  const int b   = blockIdx.z;

  // float4 index of (b, t=tc*TSTEP, n0, f=0):  ((b*TT+t)*NN + n0)*FF / 4
  const float4* p = x4 + ((size_t)(b * TT + tc * TSTEP) * NN + n0) / 2;
  float s0 = 0.0f, s1 = 0.0f;
  unsigned int c0 = 0, c1 = 0;
#pragma unroll 12
  for (int t = 0; t < TSTEP; ++t) {
    float4 v = p[(size_t)t * (NN / 2)];
    bool v0 = (v.x != NULLV);
    bool v1 = (v.z != NULLV);
    s0 += v0 ? v.x : 0.0f;  c0 += v0 ? 1u : 0u;
    s1 += v1 ? v.z : 0.0f;  c1 += v1 ? 1u : 0u;
  }
  const size_t o2 = (((size_t)tc * BB + b) * NN + n0) / 2;
  psum2[o2] = make_float2(s0, s1);
  pcnt2[o2] = make_int2((int)c0, (int)c1);

  // block total -> bsum/bcnt[blockLinear]  (plain store, no atomics)
  float rs = s0 + s1;
  unsigned int rc = c0 + c1;
  for (int off = 32; off > 0; off >>= 1) {
    rs += __shfl_down(rs, off);
    rc += __shfl_down(rc, off);
  }
  __shared__ float sh_s[4];
  __shared__ unsigned int sh_c[4];
  const int wid = tid >> 6;
  if ((tid & 63) == 0) { sh_s[wid] = rs; sh_c[wid] = rc; }
  __syncthreads();
  if (tid == 0) {
    const int blk = (blockIdx.z * TC + blockIdx.y) * 8 + blockIdx.x;
    bsum[blk] = sh_s[0] + sh_s[1] + sh_s[2] + sh_s[3];
    bcnt[blk] = sh_c[0] + sh_c[1] + sh_c[2] + sh_c[3];
  }
}

// ---------------------------------------------------------------------------
// Kernel 2: 64 blocks x 256 threads; each thread owns 4 consecutive nodes.
// (a) every block re-reduces the 1024-entry bsum/bcnt (8 KB, L2-hot) to get
//     the global imputation mean; (b) combines TC partials, imputes, writes
//     the horizon-tiled [B,H,N] prediction with float4 stores; (c) LDS
//     region histogram -> per-block rsB (plain store, no global atomics).
// ---------------------------------------------------------------------------
__global__ __launch_bounds__(256) void k_pred(
    const float4* __restrict__ psum4, const int4* __restrict__ pcnt4,
    const float4* __restrict__ bsum4, const uint4* __restrict__ bcnt4,
    const int4* __restrict__ cluster4,
    float4* __restrict__ out4, float* __restrict__ rsB) {
  const int tid = threadIdx.x;
  const int blk = blockIdx.x;          // 64 blocks
  const int b   = blk >> 2;
  const int n0  = (blk & 3) * 1024 + tid * 4;

  // ---- (a) global mean from the 1024 block totals ----
  float4 bs = bsum4[tid];              // 256 threads x 4 = 1024 entries
  uint4  bc = bcnt4[tid];
  float rs = bs.x + bs.y + bs.z + bs.w;
  unsigned int rc = bc.x + bc.y + bc.z + bc.w;
  for (int off = 32; off > 0; off >>= 1) {
    rs += __shfl_down(rs, off);
    rc += __shfl_down(rc, off);
  }
  __shared__ float sh_s[4];
  __shared__ unsigned int sh_c[4];
  __shared__ float sh_gmean;
  const int wid = tid >> 6;
  if ((tid & 63) == 0) { sh_s[wid] = rs; sh_c[wid] = rc; }
  __syncthreads();
  if (tid == 0) {
    float gs = sh_s[0] + sh_s[1] + sh_s[2] + sh_s[3];
    float gc = (float)(sh_c[0] + sh_c[1] + sh_c[2] + sh_c[3]);
    sh_gmean = gs / fmaxf(gc, 1.0f);
  }
  __syncthreads();
  const float gmean = sh_gmean;

  // ---- (b) combine partials, impute, tile over horizon ----
  float4 s = make_float4(0.f, 0.f, 0.f, 0.f);
  int4 c = make_int4(0, 0, 0, 0);
#pragma unroll
  for (int tc = 0; tc < TC; ++tc) {
    const size_t o4 = (((size_t)tc * BB + b) * NN + n0) / 4;
    float4 ps = psum4[o4];
    int4   pc = pcnt4[o4];
    s.x += ps.x; s.y += ps.y; s.z += ps.z; s.w += ps.w;
    c.x += pc.x; c.y += pc.y; c.z += pc.z; c.w += pc.w;
  }
  const float inv_t = 1.0f / (float)TT;
  float4 pred;
  pred.x = (s.x + (float)(TT - c.x) * gmean) * inv_t;
  pred.y = (s.y + (float)(TT - c.y) * gmean) * inv_t;
  pred.z = (s.z + (float)(TT - c.z) * gmean) * inv_t;
  pred.w = (s.w + (float)(TT - c.w) * gmean) * inv_t;

#pragma unroll
  for (int h = 0; h < HH; ++h)
    out4[((size_t)(b * HH + h) * NN + n0) / 4] = pred;

  // ---- (c) per-block regional sums ----
  __shared__ float rsh[RR];
  if (tid < RR) rsh[tid] = 0.0f;
  __syncthreads();
  int4 cl = cluster4[n0 / 4];
  atomicAdd(&rsh[cl.x], pred.x);
  atomicAdd(&rsh[cl.y], pred.y);
  atomicAdd(&rsh[cl.z], pred.z);
  atomicAdd(&rsh[cl.w], pred.w);
  __syncthreads();
  if (tid < RR) rsB[blk * RR + tid] = rsh[tid];
}

// ---------------------------------------------------------------------------
// Kernel 3: single block. Region histogram from cluster_id, combine the 4
// per-quarter block sums per (b,region), divide, write tiled [B,H,R].
// ---------------------------------------------------------------------------
__global__ __launch_bounds__(256) void k_final(
    const int* __restrict__ cluster, const float* __restrict__ rsB,
    float* __restrict__ out2) {
  __shared__ unsigned int hist[RR];
  const int tid = threadIdx.x;
  if (tid < RR) hist[tid] = 0u;
  __syncthreads();
  for (int i = tid; i < NN; i += 256) atomicAdd(&hist[cluster[i]], 1u);
  __syncthreads();
  const int b = tid >> 4;
  const int r = tid & 15;
  float s = 0.0f;
#pragma unroll
  for (int q = 0; q < 4; ++q) s += rsB[((b << 2) + q) * RR + r];
  const float v = s / fmaxf((float)hist[r], 1.0f);
#pragma unroll
  for (int h = 0; h < HH; ++h)
    out2[(size_t)(b * HH + h) * RR + r] = v;
}

extern "C" void kernel_launch(void* const* d_in, const int* in_sizes, int n_in,
                              void* d_out, int out_size, void* d_ws, size_t ws_size,
                              hipStream_t stream) {
  const float* x       = (const float*)d_in[0];  // [B,T,N,F] fp32
  const int*   cluster = (const int*)d_in[1];    // [N] int32
  float* out = (float*)d_out;                    // [B,H,N] then [B,H,R]

  // Workspace layout (every byte written before read each call; no zeroing):
  //   @0      psum  float[TC*BB*NN]   (2 MB)
  //   @2MB    pcnt  int[TC*BB*NN]     (2 MB)
  //   @4MB    bsum  float[1024]
  //   @4MB+4K bcnt  uint[1024]
  //   @4MB+8K rsB   float[64*16]
  float*        psum = (float*)d_ws;
  int*          pcnt = (int*)((char*)d_ws + (size_t)TC * BB * NN * 4);
  float*        bsum = (float*)((char*)d_ws + (size_t)2 * TC * BB * NN * 4);
  unsigned int* bcnt = (unsigned int*)((char*)bsum + 4096);
  float*        rsB  = (float*)((char*)bsum + 8192);

  dim3 g1(NN / 512, TC, BB);
  k_partial<<<g1, 256, 0, stream>>>((const float4*)x, (float2*)psum,
                                    (int2*)pcnt, bsum, bcnt);

  k_pred<<<64, 256, 0, stream>>>((const float4*)psum, (const int4*)pcnt,
                                 (const float4*)bsum, (const uint4*)bcnt,
                                 (const int4*)cluster, (float4*)out, rsB);

  k_final<<<1, 256, 0, stream>>>(cluster, rsB, out + (size_t)BB * HH * NN);
}